// Round 10
// baseline (245.505 us; speedup 1.0000x reference)
//
#include <hip/hip_runtime.h>
#include <hip/hip_bf16.h>
#include <hip/hip_fp8.h>
#include <stdint.h>

typedef __bf16 bf16;
typedef __attribute__((ext_vector_type(8))) short short8;
typedef __attribute__((ext_vector_type(4))) float f32x4;
typedef __attribute__((ext_vector_type(4))) bf16 bf16x4;
typedef __attribute__((ext_vector_type(8))) int int8v;
typedef __attribute__((ext_vector_type(4))) int int4v;

#define DIM 512
#define NBATCH 8
#define SEQ 2048

// async global->LDS, 16B per lane; LDS dest must be wave-uniform base + lane*16
__device__ __forceinline__ void gld_lds16(const void* g, void* l) {
    __builtin_amdgcn_global_load_lds(
        (const __attribute__((address_space(1))) void*)g,
        (__attribute__((address_space(3))) void*)l,
        16, 0, 0);
}

__device__ __forceinline__ unsigned char f32_to_e4m3(float v) {
#if __has_builtin(__builtin_amdgcn_cvt_pk_fp8_f32)
    return (unsigned char)(__builtin_amdgcn_cvt_pk_fp8_f32(v, v, 0, false) & 0xff);
#else
    return __hip_cvt_float_to_fp8(v, __HIP_SATFINITE, __HIP_E4M3);
#endif
}

// ---------------------------------------------------------------------------
// bf16 bt-GEMM: 128x128 tile, BK=64, double-buffered LDS.
// Plain __launch_bounds__(256): R9 showed (256,3) regressed gemm time 15%
// (VGPR 80->76, no occupancy gain) — the allocator constraint is pure loss.
// MODE 0: C bf16 row-major [M][N] (+bias if non-null)      [Wvo^T build]
// MODE 3: QKV/U split: all three outputs fp8(x32) row-major [16384][512] at
//         Cv + sub*8388608 (sub = col/512).  cols 1024.. carry U = x@Wvo+bvo.
// SWIZ 0: plain 2D grid.  SWIZ 2: xcd=g&7, column-siblings share an XCD.
// ---------------------------------------------------------------------------
template <int MODE, int SWIZ>
__global__ __launch_bounds__(256) void gemm_bt(
    const bf16* __restrict__ A, const bf16* __restrict__ Bt,
    void* __restrict__ Cv, const float* __restrict__ bias,
    int N, int K, int gx)
{
    __shared__ bf16 smem[32768];
    bf16* Asb = smem;
    bf16* Bsb = smem + 16384;

    int bx, by;
    if (SWIZ == 2) {
        const unsigned g = blockIdx.x;
        const unsigned xcd = g & 7;
        const unsigned t = g >> 3;
        const unsigned per = (gridDim.x >> 3) / (unsigned)gx;
        by = xcd * per + t / (unsigned)gx;
        bx = t % (unsigned)gx;
    } else {
        bx = blockIdx.x; by = blockIdx.y;
    }

    const int tid  = threadIdx.x;
    const int lane = tid & 63;
    const int w    = tid >> 6;
    const int wr   = w >> 1;
    const int wc   = w & 1;
    const int lm   = lane & 15;
    const int lk   = lane >> 4;
    const int fs   = lm & 7;
    const int rq   = tid >> 3;
    const int pc   = tid & 7;
    const int scol = ((pc ^ (rq & 7)) * 8);

    const bf16* Ag = A + (size_t)(by * 128) * K;
    const bf16* Bg = Bt + (size_t)(bx * 128) * K;

    f32x4 acc[4][4];
#pragma unroll
    for (int i = 0; i < 4; ++i)
#pragma unroll
        for (int j = 0; j < 4; ++j)
            acc[i][j] = (f32x4){0.f, 0.f, 0.f, 0.f};

    auto stage = [&](int kb, int buf) {
#pragma unroll
        for (int t = 0; t < 4; ++t) {
            const int r = t * 32 + rq;
            gld_lds16(Ag + (size_t)r * K + kb + scol,
                      Asb + buf * 8192 + t * 2048 + tid * 8);
            gld_lds16(Bg + (size_t)r * K + kb + scol,
                      Bsb + buf * 8192 + t * 2048 + tid * 8);
        }
    };
    auto compute = [&](int buf) {
        const bf16* Ab = Asb + buf * 8192;
        const bf16* Bb = Bsb + buf * 8192;
#pragma unroll
        for (int s = 0; s < 2; ++s) {
            const int u = ((s * 4 + lk) ^ fs) * 8;
            short8 fa[4], fb[4];
#pragma unroll
            for (int i = 0; i < 4; ++i)
                fa[i] = *(const short8*)&Ab[(wr * 64 + i * 16 + lm) * 64 + u];
#pragma unroll
            for (int j = 0; j < 4; ++j)
                fb[j] = *(const short8*)&Bb[(wc * 64 + j * 16 + lm) * 64 + u];
#pragma unroll
            for (int i = 0; i < 4; ++i)
#pragma unroll
                for (int j = 0; j < 4; ++j)
                    acc[i][j] = __builtin_amdgcn_mfma_f32_16x16x32_bf16(
                        fa[i], fb[j], acc[i][j], 0, 0, 0);
        }
    };

    stage(0, 0);
    __syncthreads();
    const int E = K >> 6;
#pragma unroll 2
    for (int e = 0; e < E; ++e) {
        if (e + 1 < E) stage((e + 1) << 6, (e + 1) & 1);
        compute(e & 1);
        __syncthreads();
    }

    // bias add (MODE 0 optional, MODE 3 always has bias)
#pragma unroll
    for (int i = 0; i < 4; ++i)
#pragma unroll
        for (int j = 0; j < 4; ++j) {
            const int col = bx * 128 + wc * 64 + j * 16 + lm;
            const float bv = bias ? bias[col] : 0.0f;
#pragma unroll
            for (int r = 0; r < 4; ++r)
                acc[i][j][r] += bv;
        }

    if (MODE == 0) {
        bf16* dst = (bf16*)Cv;
        const int col0 = bx * 128;
#pragma unroll
        for (int h = 0; h < 2; ++h) {
            if (wr == h) {
#pragma unroll
                for (int i = 0; i < 4; ++i)
#pragma unroll
                    for (int j = 0; j < 4; ++j)
#pragma unroll
                        for (int r = 0; r < 4; ++r)
                            smem[(i * 16 + lk * 4 + r) * 136 + wc * 64 + j * 16 + lm] =
                                (bf16)acc[i][j][r];
            }
            __syncthreads();
            const int rr0 = tid >> 4, cc = (tid & 15) * 8;
#pragma unroll
            for (int p = 0; p < 4; ++p) {
                const int row = p * 16 + rr0;
                const uint4 raw = *(const uint4*)&smem[row * 136 + cc];
                *(uint4*)&dst[(size_t)(by * 128 + h * 64 + row) * N + col0 + cc] =
                    raw;
            }
            __syncthreads();
        }
        return;
    }

    // MODE 3: fp8(x32) writer via LDS [64][144] tile halves
    const int sub  = (bx * 128) >> 9;          // 0=Q 1=K 2=U
    const int col0 = (bx * 128) & 511;
    uint8_t* d8 = (uint8_t*)Cv + (size_t)sub * 8388608;
    uint8_t* t8 = (uint8_t*)smem;
#pragma unroll
    for (int h = 0; h < 2; ++h) {
        if (wr == h) {
#pragma unroll
            for (int i = 0; i < 4; ++i)
#pragma unroll
                for (int j = 0; j < 4; ++j)
#pragma unroll
                    for (int r = 0; r < 4; ++r)
                        t8[(i * 16 + lk * 4 + r) * 144 + wc * 64 + j * 16 + lm] =
                            f32_to_e4m3(32.0f * acc[i][j][r]);
        }
        __syncthreads();
        const int rr = tid >> 3, cc = (tid & 7) * 16;
#pragma unroll
        for (int p = 0; p < 2; ++p) {
            const int row = p * 32 + rr;
            const uint4 raw = *(const uint4*)&t8[row * 144 + cc];
            *(uint4*)&d8[(size_t)(by * 128 + h * 64 + row) * 512 + col0 + cc] =
                raw;
        }
        __syncthreads();
    }
}

// ---------------------------------------------------------------------------
// MX fp8 bt-GEMM (attention): 128x128 tile, BK=128, single buffer.
// mfma_scale_f32_16x16x128_f8f6f4, unit e8m0 scales (127) = plain e4m3 GEMM.
// Plain launch bounds (R9: min-waves hint regressed 15%).
// MODE 4: S8 = e4m3(exp(alpha*acc)); fp32 row sums atomicAdd into rsum.
// MODE 5: OUT fp32 = acc / (32*rsum[row])  (PV + normalize + final output:
//         out-projection folded into U = x@(Wv@Wo)+bvo, P rows sum to 1).
// ---------------------------------------------------------------------------
template <int MODE>
__global__ __launch_bounds__(256) void gemm_mx(
    const uint8_t* __restrict__ A, const uint8_t* __restrict__ Bt,
    void* __restrict__ Cv, float* __restrict__ rsum,
    int N, int K, long long sA, long long sB, long long sC, float alpha,
    int gx)
{
    __shared__ uint8_t smem[33792];      // K-loop uses 32 KB; MODE5 ft 33 KB
    uint8_t* As = smem;
    uint8_t* Bs = smem + 16384;

    int bx, by, bz;
    {
        const unsigned g = blockIdx.x;
        bz = g & 7;
        const unsigned r = g >> 3;
        bx = r % (unsigned)gx;
        by = r / (unsigned)gx;
    }

    const int tid  = threadIdx.x;
    const int lane = tid & 63;
    const int w    = tid >> 6;
    const int wr   = w >> 1;
    const int wc   = w & 1;
    const int lm   = lane & 15;
    const int lk   = lane >> 4;
    const int rq   = tid >> 3;
    const int pc   = tid & 7;
    const int ssrc = (pc ^ (rq & 7)) * 16;
    const int ca   = ((2 * lk) ^ (lm & 7)) * 16;
    const int cb   = ((2 * lk + 1) ^ (lm & 7)) * 16;

    const size_t z = bz;
    const uint8_t* Ag = A + z * (size_t)sA + (size_t)(by * 128) * K;
    const uint8_t* Bg = Bt + z * (size_t)sB + (size_t)(bx * 128) * K;

    f32x4 acc[4][4];
#pragma unroll
    for (int i = 0; i < 4; ++i)
#pragma unroll
        for (int j = 0; j < 4; ++j)
            acc[i][j] = (f32x4){0.f, 0.f, 0.f, 0.f};

    for (int kb = 0; kb < K; kb += 128) {
#pragma unroll
        for (int t = 0; t < 4; ++t) {
            const int r = t * 32 + rq;
            gld_lds16(Ag + (size_t)r * K + kb + ssrc, As + t * 4096 + tid * 16);
            gld_lds16(Bg + (size_t)r * K + kb + ssrc, Bs + t * 4096 + tid * 16);
        }
        __syncthreads();

        int8v fa[4];
#pragma unroll
        for (int i = 0; i < 4; ++i) {
            const uint8_t* rp = As + (wr * 64 + i * 16 + lm) * 128;
            const int4v lo = *(const int4v*)(rp + ca);
            const int4v hi = *(const int4v*)(rp + cb);
            fa[i] = (int8v){lo[0], lo[1], lo[2], lo[3], hi[0], hi[1], hi[2], hi[3]};
        }
#pragma unroll
        for (int j = 0; j < 4; ++j) {
            const uint8_t* rp = Bs + (wc * 64 + j * 16 + lm) * 128;
            const int4v lo = *(const int4v*)(rp + ca);
            const int4v hi = *(const int4v*)(rp + cb);
            const int8v fb = (int8v){lo[0], lo[1], lo[2], lo[3],
                                     hi[0], hi[1], hi[2], hi[3]};
#pragma unroll
            for (int i = 0; i < 4; ++i)
                acc[i][j] = __builtin_amdgcn_mfma_scale_f32_16x16x128_f8f6f4(
                    fa[i], fb, acc[i][j], 0, 0, 0, 127, 0, 127);
        }
        __syncthreads();
    }

    const int orow0 = by * 128 + wr * 64;

    if (MODE == 4) {
#pragma unroll
        for (int i = 0; i < 4; ++i) {
            float psum[4] = {0.f, 0.f, 0.f, 0.f};
#pragma unroll
            for (int j = 0; j < 4; ++j)
#pragma unroll
                for (int r = 0; r < 4; ++r) {
                    const float e = __expf(acc[i][j][r] * alpha);
                    acc[i][j][r] = e;
                    psum[r] += e;
                }
#pragma unroll
            for (int m = 1; m < 16; m <<= 1)
#pragma unroll
                for (int r = 0; r < 4; ++r) psum[r] += __shfl_xor(psum[r], m);
            if (lm == 0) {
#pragma unroll
                for (int r = 0; r < 4; ++r)
                    atomicAdd(&rsum[z * SEQ + orow0 + i * 16 + lk * 4 + r],
                              psum[r]);
            }
        }
        uint8_t* dst = (uint8_t*)Cv + z * (size_t)sC;
#pragma unroll
        for (int h = 0; h < 2; ++h) {
            if (wr == h) {
#pragma unroll
                for (int i = 0; i < 4; ++i)
#pragma unroll
                    for (int j = 0; j < 4; ++j)
#pragma unroll
                        for (int r = 0; r < 4; ++r)
                            smem[(i * 16 + lk * 4 + r) * 144 +
                                 wc * 64 + j * 16 + lm] =
                                f32_to_e4m3(acc[i][j][r]);
            }
            __syncthreads();
            const int rr = tid >> 3, cc = (tid & 7) * 16;
#pragma unroll
            for (int p = 0; p < 2; ++p) {
                const int row = p * 32 + rr;
                const uint4 raw = *(const uint4*)&smem[row * 144 + cc];
                *(uint4*)&dst[(size_t)(by * 128 + h * 64 + row) * N +
                              bx * 128 + cc] = raw;
            }
            __syncthreads();
        }
        return;
    }

    // MODE 5: normalize by 32*rowsum, fp32 final-output writer (float4)
#pragma unroll
    for (int i = 0; i < 4; ++i) {
        float inv[4];
#pragma unroll
        for (int r = 0; r < 4; ++r)
            inv[r] = 1.0f / (32.0f * rsum[z * SEQ + orow0 + i * 16 + lk * 4 + r]);
#pragma unroll
        for (int j = 0; j < 4; ++j)
#pragma unroll
            for (int r = 0; r < 4; ++r)
                acc[i][j][r] *= inv[r];
    }
    float* dst = (float*)Cv + z * (size_t)sC;
    float* ft = (float*)smem;            // [64][132] floats = 33792 B
#pragma unroll
    for (int h = 0; h < 2; ++h) {
        if (wr == h) {
#pragma unroll
            for (int i = 0; i < 4; ++i)
#pragma unroll
                for (int j = 0; j < 4; ++j)
#pragma unroll
                    for (int r = 0; r < 4; ++r)
                        ft[(i * 16 + lk * 4 + r) * 132 + wc * 64 + j * 16 + lm] =
                            acc[i][j][r];
        }
        __syncthreads();
        const int rr = tid >> 5, cc = (tid & 31) * 4;
#pragma unroll
        for (int p = 0; p < 8; ++p) {
            const int row = p * 8 + rr;
            *(float4*)&dst[(size_t)(by * 128 + h * 64 + row) * N + bx * 128 + cc] =
                *(const float4*)&ft[row * 132 + cc];
        }
        __syncthreads();
    }
}

// ---------------------------------------------------------------------------
// U8 [8][2048][512] fp8 -> Ut8 [8][512][2048] fp8 byte-permute, 64x64 tiles.
// ---------------------------------------------------------------------------
__global__ __launch_bounds__(256) void transpose_v8(
    const uint8_t* __restrict__ V, uint8_t* __restrict__ Vt)
{
    __shared__ uint8_t tile[64][68];
    const int b = blockIdx.z, tx = blockIdx.x, ty = blockIdx.y;
    const int t0 = threadIdx.x;
    const int r = t0 >> 2, c0 = (t0 & 3) * 16;
    *(uint4*)&tile[r][c0] =
        *(const uint4*)&V[((size_t)b * SEQ + ty * 64 + r) * 512 + tx * 64 + c0];
    __syncthreads();
    const int o = t0 >> 2, i0 = (t0 & 3) * 16;
    uint4 pk;
    uint8_t* pb = (uint8_t*)&pk;
#pragma unroll
    for (int j = 0; j < 16; ++j) pb[j] = tile[i0 + j][o];
    *(uint4*)&Vt[((size_t)b * 512 + tx * 64 + o) * SEQ + ty * 64 + i0] = pk;
}

// ---------------------------------------------------------------------------
__global__ __launch_bounds__(256) void cvt_f32_bf16(
    const float* __restrict__ x, bf16* __restrict__ o, int n4)
{
    const int i = blockIdx.x * 256 + threadIdx.x;
    if (i >= n4) return;
    const float4 v = ((const float4*)x)[i];
    bf16x4 b;
    b[0] = (bf16)v.x; b[1] = (bf16)v.y; b[2] = (bf16)v.z; b[3] = (bf16)v.w;
    ((bf16x4*)o)[i] = b;
}

// ---------------------------------------------------------------------------
// Prologue kernel, grid (8,8,6):
//  z=0: Wq^T -> Wcat[0..511]      z=1: Wk^T -> Wcat[512..1023]
//  z=2: Wv   -> Wvb (plain bf16)  z=3: Wo^T -> Wto
//  z=4: zero rowsum[16384], pack bcat[0..1023] = bq|bk
//  z=5: bcat[1024+j] = bvo[j] = sum_k bv[k]*Wo[k][j] + bo[j]
// ---------------------------------------------------------------------------
__global__ __launch_bounds__(256) void prep(
    const float* __restrict__ Wq, const float* __restrict__ Wk,
    const float* __restrict__ Wv, const float* __restrict__ Wo,
    bf16* __restrict__ Wcat, bf16* __restrict__ Wto, bf16* __restrict__ Wvb,
    const float* __restrict__ bq, const float* __restrict__ bk,
    const float* __restrict__ bv, const float* __restrict__ bo,
    float* __restrict__ bcat, float* __restrict__ rowsum)
{
    const int widx = blockIdx.z;
    const int t0 = threadIdx.x;
    if (widx == 4) {
        const int idx = (blockIdx.y * 8 + blockIdx.x) * 256 + t0;
        rowsum[idx] = 0.0f;
        if (idx < 1024) bcat[idx] = (idx < 512) ? bq[idx] : bk[idx - 512];
        return;
    }
    if (widx == 5) {
        const int idx = (blockIdx.y * 8 + blockIdx.x) * 256 + t0;
        if (idx < 512) {
            float s = bo[idx];
#pragma unroll 8
            for (int k = 0; k < 512; ++k)
                s += bv[k] * Wo[k * 512 + idx];
            bcat[1024 + idx] = s;
        }
        return;
    }
    const int tx = blockIdx.x, ty = blockIdx.y;
    if (widx == 2) {
        // plain bf16 copy of Wv (B-operand for the Wvo^T build)
#pragma unroll
        for (int it = 0; it < 16; ++it) {
            const int e = it * 256 + t0;
            const int r = e >> 6, c = e & 63;
            const size_t lin = (size_t)(ty * 64 + r) * 512 + tx * 64 + c;
            Wvb[lin] = (bf16)Wv[lin];
        }
        return;
    }
    __shared__ bf16 tile[64][65];
    const float* W = (widx == 0) ? Wq : (widx == 1) ? Wk : Wo;
    bf16* dst = (widx == 0) ? Wcat : (widx == 1) ? (Wcat + 512 * 512) : Wto;
#pragma unroll
    for (int it = 0; it < 16; ++it) {
        const int e = it * 256 + t0;
        const int r = e >> 6, c = e & 63;
        tile[r][c] = (bf16)W[(size_t)(ty * 64 + r) * 512 + tx * 64 + c];
    }
    __syncthreads();
#pragma unroll
    for (int it = 0; it < 16; ++it) {
        const int e = it * 256 + t0;
        const int o = e >> 6, i = e & 63;
        dst[(size_t)(tx * 64 + o) * 512 + ty * 64 + i] = tile[i][o];
    }
}

// ---------------------------------------------------------------------------
extern "C" void kernel_launch(void* const* d_in, const int* in_sizes, int n_in,
                              void* d_out, int out_size, void* d_ws, size_t ws_size,
                              hipStream_t stream)
{
    const float* x  = (const float*)d_in[0];
    const float* Wq = (const float*)d_in[1];
    const float* bq = (const float*)d_in[2];
    const float* Wk = (const float*)d_in[3];
    const float* bk = (const float*)d_in[4];
    const float* Wv = (const float*)d_in[5];
    const float* bv = (const float*)d_in[6];
    const float* Wo = (const float*)d_in[7];
    const float* bo = (const float*)d_in[8];
    float* out = (float*)d_out;

    char* ws = (char*)d_ws;
    bf16*    Xb     = (bf16*)(ws);              // 16 MB
    bf16*    Wcat   = (bf16*)(ws + 16777216);   // 1536x512 bf16 (Wq^T|Wk^T|Wvo^T)
    bf16*    Wto    = (bf16*)(ws + 18350080);   // 0.5 MB  Wo^T
    float*   bcat   = (float*)(ws + 18874368);  // 1536 fp32 (bq|bk|bvo)
    float*   rowsum = (float*)(ws + 18880512);  // 64 KB
    bf16*    Wvb    = (bf16*)(ws + 18946048);   // 0.5 MB plain-bf16 Wv
    uint8_t* Q8     = (uint8_t*)(ws + 20971520);  // Q8|K8|U8 fp8, 8 MB each
    uint8_t* K8     = (uint8_t*)(ws + 29360128);
    uint8_t* U8     = (uint8_t*)(ws + 37748736);
    uint8_t* Ut8    = (uint8_t*)(ws + 54525952);  // [8][512][2048] fp8, 8 MB
    uint8_t* S8     = (uint8_t*)(ws + 62914560);  // [8][2048][2048] fp8, 33.5 MB

    // prologue: weight transposes + Wvb + bcat(bq|bk|bvo) + rowsum zero
    prep<<<dim3(8, 8, 6), 256, 0, stream>>>(
        Wq, Wk, Wv, Wo, Wcat, Wto, Wvb, bq, bk, bv, bo, bcat, rowsum);

    // Wvo^T = Wo^T @ (Wvb)^T -> Wcat rows 1024..1535  (16-block bf16 GEMM)
    gemm_bt<0, 0><<<dim3(4, 4), 256, 0, stream>>>(
        Wto, Wvb, Wcat + 1024 * 512, nullptr, 512, 512, 0);

    cvt_f32_bf16<<<8192, 256, 0, stream>>>(x, Xb, 2097152);

    const float scale = 0.044194173824159216f;  // 512^-0.5

    // Fused projection: [Q8|K8|U8] = fp8(32*(x @ [Wq|Wk|Wvo] + [bq|bk|bvo]))
    gemm_bt<3, 2><<<1536, 256, 0, stream>>>(
        Xb, Wcat, Q8, bcat, 1536, 512, 12);

    // U8 -> Ut8 byte-permute transpose
    transpose_v8<<<dim3(8, 32, 8), 256, 0, stream>>>(U8, Ut8);

    // S8 = e4m3(exp(scale/1024 * Q8 @ K8^T)) + row sums; per batch 2048x2048
    gemm_mx<4><<<2048, 256, 0, stream>>>(
        Q8, K8, S8, rowsum, 2048, 512,
        2048LL * 512, 2048LL * 512, 2048LL * 2048, scale / 1024.0f, 16);

    // out = (S8 @ Ut8^T) / (32*rowsum)  — final fp32 output, no out-proj
    gemm_mx<5><<<512, 256, 0, stream>>>(
        S8, Ut8, out, rowsum, 512, 2048,
        2048LL * 2048, 512LL * 2048, 2048LL * 512, 1.0f, 4);
}

// Round 11
// 222.024 us; speedup vs baseline: 1.1058x; 1.1058x over previous
//
#include <hip/hip_runtime.h>
#include <hip/hip_bf16.h>
#include <hip/hip_fp8.h>
#include <stdint.h>

typedef __bf16 bf16;
typedef __attribute__((ext_vector_type(8))) short short8;
typedef __attribute__((ext_vector_type(4))) float f32x4;
typedef __attribute__((ext_vector_type(4))) bf16 bf16x4;
typedef __attribute__((ext_vector_type(8))) int int8v;
typedef __attribute__((ext_vector_type(4))) int int4v;

#define DIM 512
#define NBATCH 8
#define SEQ 2048

// async global->LDS, 16B per lane; LDS dest must be wave-uniform base + lane*16
__device__ __forceinline__ void gld_lds16(const void* g, void* l) {
    __builtin_amdgcn_global_load_lds(
        (const __attribute__((address_space(1))) void*)g,
        (__attribute__((address_space(3))) void*)l,
        16, 0, 0);
}

__device__ __forceinline__ unsigned char f32_to_e4m3(float v) {
#if __has_builtin(__builtin_amdgcn_cvt_pk_fp8_f32)
    return (unsigned char)(__builtin_amdgcn_cvt_pk_fp8_f32(v, v, 0, false) & 0xff);
#else
    return __hip_cvt_float_to_fp8(v, __HIP_SATFINITE, __HIP_E4M3);
#endif
}

// ---------------------------------------------------------------------------
// bf16 bt-GEMM: 128x128 tile, BK=64, double-buffered LDS, plain launch bounds
// (R9/R10 A-B: the (256,3) min-waves hint regressed 15% with no occupancy
// gain — allocator freedom wins). R10 lesson: keep dispatches WIDE; never
// trade a 512-block GEMM for a 16-block one (serial latency dominates).
// MODE 2: C fp32 row-major [M][N], +bias  (out-projection).
// MODE 3: QKV split: Q/K/V all fp8(x32) row-major [16384][512] at
//         Cv + sub*8388608 (sub = col/512).
// SWIZ 2: 1D grid, xcd=g&7; column-sibling blocks share an XCD (L2 reuse).
// ---------------------------------------------------------------------------
template <int MODE, int SWIZ>
__global__ __launch_bounds__(256) void gemm_bt(
    const bf16* __restrict__ A, const bf16* __restrict__ Bt,
    void* __restrict__ Cv, const float* __restrict__ bias,
    int N, int K, int gx)
{
    __shared__ bf16 smem[32768];
    bf16* Asb = smem;
    bf16* Bsb = smem + 16384;

    int bx, by;
    {
        const unsigned g = blockIdx.x;
        const unsigned xcd = g & 7;
        const unsigned t = g >> 3;
        const unsigned per = (gridDim.x >> 3) / (unsigned)gx;
        by = xcd * per + t / (unsigned)gx;
        bx = t % (unsigned)gx;
    }

    const int tid  = threadIdx.x;
    const int lane = tid & 63;
    const int w    = tid >> 6;
    const int wr   = w >> 1;
    const int wc   = w & 1;
    const int lm   = lane & 15;
    const int lk   = lane >> 4;
    const int fs   = lm & 7;
    const int rq   = tid >> 3;
    const int pc   = tid & 7;
    const int scol = ((pc ^ (rq & 7)) * 8);

    const bf16* Ag = A + (size_t)(by * 128) * K;
    const bf16* Bg = Bt + (size_t)(bx * 128) * K;

    f32x4 acc[4][4];
#pragma unroll
    for (int i = 0; i < 4; ++i)
#pragma unroll
        for (int j = 0; j < 4; ++j)
            acc[i][j] = (f32x4){0.f, 0.f, 0.f, 0.f};

    auto stage = [&](int kb, int buf) {
#pragma unroll
        for (int t = 0; t < 4; ++t) {
            const int r = t * 32 + rq;
            gld_lds16(Ag + (size_t)r * K + kb + scol,
                      Asb + buf * 8192 + t * 2048 + tid * 8);
            gld_lds16(Bg + (size_t)r * K + kb + scol,
                      Bsb + buf * 8192 + t * 2048 + tid * 8);
        }
    };
    auto compute = [&](int buf) {
        const bf16* Ab = Asb + buf * 8192;
        const bf16* Bb = Bsb + buf * 8192;
#pragma unroll
        for (int s = 0; s < 2; ++s) {
            const int u = ((s * 4 + lk) ^ fs) * 8;
            short8 fa[4], fb[4];
#pragma unroll
            for (int i = 0; i < 4; ++i)
                fa[i] = *(const short8*)&Ab[(wr * 64 + i * 16 + lm) * 64 + u];
#pragma unroll
            for (int j = 0; j < 4; ++j)
                fb[j] = *(const short8*)&Bb[(wc * 64 + j * 16 + lm) * 64 + u];
#pragma unroll
            for (int i = 0; i < 4; ++i)
#pragma unroll
                for (int j = 0; j < 4; ++j)
                    acc[i][j] = __builtin_amdgcn_mfma_f32_16x16x32_bf16(
                        fa[i], fb[j], acc[i][j], 0, 0, 0);
        }
    };

    stage(0, 0);
    __syncthreads();
    const int E = K >> 6;
#pragma unroll 2
    for (int e = 0; e < E; ++e) {
        if (e + 1 < E) stage((e + 1) << 6, (e + 1) & 1);
        compute(e & 1);
        __syncthreads();
    }

    // bias add
#pragma unroll
    for (int i = 0; i < 4; ++i)
#pragma unroll
        for (int j = 0; j < 4; ++j) {
            const int col = bx * 128 + wc * 64 + j * 16 + lm;
            const float bv = bias[col];
#pragma unroll
            for (int r = 0; r < 4; ++r)
                acc[i][j][r] += bv;
        }

    if (MODE == 2) {
        // fp32 out via LDS-coalesced float4 stores; ft = [64][132] floats
        float* ft = (float*)smem;
        float* outp = (float*)Cv;
#pragma unroll
        for (int h = 0; h < 2; ++h) {
            if (wr == h) {
#pragma unroll
                for (int i = 0; i < 4; ++i)
#pragma unroll
                    for (int j = 0; j < 4; ++j)
#pragma unroll
                        for (int r = 0; r < 4; ++r)
                            ft[(i * 16 + lk * 4 + r) * 132 + wc * 64 + j * 16 + lm] =
                                acc[i][j][r];
            }
            __syncthreads();
            const int rr = tid >> 5, cc = (tid & 31) * 4;
#pragma unroll
            for (int p = 0; p < 8; ++p) {
                const int row = p * 8 + rr;
                *(float4*)&outp[(size_t)(by * 128 + h * 64 + row) * N +
                                bx * 128 + cc] = *(const float4*)&ft[row * 132 + cc];
            }
            __syncthreads();
        }
        return;
    }

    // MODE 3: fp8(x32) writer via LDS [64][144] tile halves
    const int sub  = (bx * 128) >> 9;          // 0=Q 1=K 2=V
    const int col0 = (bx * 128) & 511;
    uint8_t* d8 = (uint8_t*)Cv + (size_t)sub * 8388608;
    uint8_t* t8 = (uint8_t*)smem;
#pragma unroll
    for (int h = 0; h < 2; ++h) {
        if (wr == h) {
#pragma unroll
            for (int i = 0; i < 4; ++i)
#pragma unroll
                for (int j = 0; j < 4; ++j)
#pragma unroll
                    for (int r = 0; r < 4; ++r)
                        t8[(i * 16 + lk * 4 + r) * 144 + wc * 64 + j * 16 + lm] =
                            f32_to_e4m3(32.0f * acc[i][j][r]);
        }
        __syncthreads();
        const int rr = tid >> 3, cc = (tid & 7) * 16;
#pragma unroll
        for (int p = 0; p < 2; ++p) {
            const int row = p * 32 + rr;
            const uint4 raw = *(const uint4*)&t8[row * 144 + cc];
            *(uint4*)&d8[(size_t)(by * 128 + h * 64 + row) * 512 + col0 + cc] =
                raw;
        }
        __syncthreads();
    }
}

// ---------------------------------------------------------------------------
// MX fp8 bt-GEMM (attention): 128x128 tile, BK=128, 32 KB LDS, single buffer.
// mfma_scale_f32_16x16x128_f8f6f4, unit e8m0 scales (127) = plain e4m3 GEMM.
// Plain launch bounds (R9/R10 A-B: min-waves hint = 15% regression).
// MODE 4: S8 = e4m3(exp(alpha*acc)); fp32 row sums atomicAdd into rsum.
// MODE 5: C bf16 = acc / (32*rsum[row])  (PV + normalize; V scale folds).
// ---------------------------------------------------------------------------
template <int MODE>
__global__ __launch_bounds__(256) void gemm_mx(
    const uint8_t* __restrict__ A, const uint8_t* __restrict__ Bt,
    void* __restrict__ Cv, float* __restrict__ rsum,
    int N, int K, long long sA, long long sB, long long sC, float alpha,
    int gx)
{
    __shared__ uint8_t smem[32768];
    uint8_t* As = smem;
    uint8_t* Bs = smem + 16384;

    int bx, by, bz;
    {
        const unsigned g = blockIdx.x;
        bz = g & 7;
        const unsigned r = g >> 3;
        bx = r % (unsigned)gx;
        by = r / (unsigned)gx;
    }

    const int tid  = threadIdx.x;
    const int lane = tid & 63;
    const int w    = tid >> 6;
    const int wr   = w >> 1;
    const int wc   = w & 1;
    const int lm   = lane & 15;
    const int lk   = lane >> 4;
    const int rq   = tid >> 3;
    const int pc   = tid & 7;
    const int ssrc = (pc ^ (rq & 7)) * 16;
    const int ca   = ((2 * lk) ^ (lm & 7)) * 16;
    const int cb   = ((2 * lk + 1) ^ (lm & 7)) * 16;

    const size_t z = bz;
    const uint8_t* Ag = A + z * (size_t)sA + (size_t)(by * 128) * K;
    const uint8_t* Bg = Bt + z * (size_t)sB + (size_t)(bx * 128) * K;

    f32x4 acc[4][4];
#pragma unroll
    for (int i = 0; i < 4; ++i)
#pragma unroll
        for (int j = 0; j < 4; ++j)
            acc[i][j] = (f32x4){0.f, 0.f, 0.f, 0.f};

    for (int kb = 0; kb < K; kb += 128) {
#pragma unroll
        for (int t = 0; t < 4; ++t) {
            const int r = t * 32 + rq;
            gld_lds16(Ag + (size_t)r * K + kb + ssrc, As + t * 4096 + tid * 16);
            gld_lds16(Bg + (size_t)r * K + kb + ssrc, Bs + t * 4096 + tid * 16);
        }
        __syncthreads();

        int8v fa[4];
#pragma unroll
        for (int i = 0; i < 4; ++i) {
            const uint8_t* rp = As + (wr * 64 + i * 16 + lm) * 128;
            const int4v lo = *(const int4v*)(rp + ca);
            const int4v hi = *(const int4v*)(rp + cb);
            fa[i] = (int8v){lo[0], lo[1], lo[2], lo[3], hi[0], hi[1], hi[2], hi[3]};
        }
#pragma unroll
        for (int j = 0; j < 4; ++j) {
            const uint8_t* rp = Bs + (wc * 64 + j * 16 + lm) * 128;
            const int4v lo = *(const int4v*)(rp + ca);
            const int4v hi = *(const int4v*)(rp + cb);
            const int8v fb = (int8v){lo[0], lo[1], lo[2], lo[3],
                                     hi[0], hi[1], hi[2], hi[3]};
#pragma unroll
            for (int i = 0; i < 4; ++i)
                acc[i][j] = __builtin_amdgcn_mfma_scale_f32_16x16x128_f8f6f4(
                    fa[i], fb, acc[i][j], 0, 0, 0, 127, 0, 127);
        }
        __syncthreads();
    }

    const int orow0 = by * 128 + wr * 64;

    if (MODE == 4) {
#pragma unroll
        for (int i = 0; i < 4; ++i) {
            float psum[4] = {0.f, 0.f, 0.f, 0.f};
#pragma unroll
            for (int j = 0; j < 4; ++j)
#pragma unroll
                for (int r = 0; r < 4; ++r) {
                    const float e = __expf(acc[i][j][r] * alpha);
                    acc[i][j][r] = e;
                    psum[r] += e;
                }
#pragma unroll
            for (int m = 1; m < 16; m <<= 1)
#pragma unroll
                for (int r = 0; r < 4; ++r) psum[r] += __shfl_xor(psum[r], m);
            if (lm == 0) {
#pragma unroll
                for (int r = 0; r < 4; ++r)
                    atomicAdd(&rsum[z * SEQ + orow0 + i * 16 + lk * 4 + r],
                              psum[r]);
            }
        }
        uint8_t* dst = (uint8_t*)Cv + z * (size_t)sC;
#pragma unroll
        for (int h = 0; h < 2; ++h) {
            if (wr == h) {
#pragma unroll
                for (int i = 0; i < 4; ++i)
#pragma unroll
                    for (int j = 0; j < 4; ++j)
#pragma unroll
                        for (int r = 0; r < 4; ++r)
                            smem[(i * 16 + lk * 4 + r) * 144 +
                                 wc * 64 + j * 16 + lm] =
                                f32_to_e4m3(acc[i][j][r]);
            }
            __syncthreads();
            const int rr = tid >> 3, cc = (tid & 7) * 16;
#pragma unroll
            for (int p = 0; p < 2; ++p) {
                const int row = p * 32 + rr;
                const uint4 raw = *(const uint4*)&smem[row * 144 + cc];
                *(uint4*)&dst[(size_t)(by * 128 + h * 64 + row) * N +
                              bx * 128 + cc] = raw;
            }
            __syncthreads();
        }
        return;
    }

    // MODE 5: normalize by 32*rowsum, bf16 out via LDS [64][136] tile
#pragma unroll
    for (int i = 0; i < 4; ++i) {
        float inv[4];
#pragma unroll
        for (int r = 0; r < 4; ++r)
            inv[r] = 1.0f / (32.0f * rsum[z * SEQ + orow0 + i * 16 + lk * 4 + r]);
#pragma unroll
        for (int j = 0; j < 4; ++j)
#pragma unroll
            for (int r = 0; r < 4; ++r)
                acc[i][j][r] *= inv[r];
    }
    bf16* dst = (bf16*)Cv + z * (size_t)sC;
    bf16* tile = (bf16*)smem;
#pragma unroll
    for (int h = 0; h < 2; ++h) {
        if (wr == h) {
#pragma unroll
            for (int i = 0; i < 4; ++i)
#pragma unroll
                for (int j = 0; j < 4; ++j)
#pragma unroll
                    for (int r = 0; r < 4; ++r)
                        tile[(i * 16 + lk * 4 + r) * 136 + wc * 64 + j * 16 + lm] =
                            (bf16)acc[i][j][r];
        }
        __syncthreads();
        const int rr0 = tid >> 4, cc = (tid & 15) * 8;
#pragma unroll
        for (int p = 0; p < 4; ++p) {
            const int row = p * 16 + rr0;
            const uint4 raw = *(const uint4*)&tile[row * 136 + cc];
            *(uint4*)&dst[(size_t)(by * 128 + h * 64 + row) * N + bx * 128 + cc] =
                raw;
        }
        __syncthreads();
    }
}

// ---------------------------------------------------------------------------
// V8 [8][2048][512] fp8 -> Vt8 [8][512][2048] fp8 byte-permute, 64x64 tiles.
// ---------------------------------------------------------------------------
__global__ __launch_bounds__(256) void transpose_v8(
    const uint8_t* __restrict__ V, uint8_t* __restrict__ Vt)
{
    __shared__ uint8_t tile[64][68];
    const int b = blockIdx.z, tx = blockIdx.x, ty = blockIdx.y;
    const int t0 = threadIdx.x;
    const int r = t0 >> 2, c0 = (t0 & 3) * 16;
    *(uint4*)&tile[r][c0] =
        *(const uint4*)&V[((size_t)b * SEQ + ty * 64 + r) * 512 + tx * 64 + c0];
    __syncthreads();
    const int o = t0 >> 2, i0 = (t0 & 3) * 16;
    uint4 pk;
    uint8_t* pb = (uint8_t*)&pk;
#pragma unroll
    for (int j = 0; j < 16; ++j) pb[j] = tile[i0 + j][o];
    *(uint4*)&Vt[((size_t)b * 512 + tx * 64 + o) * SEQ + ty * 64 + i0] = pk;
}

// ---------------------------------------------------------------------------
__global__ __launch_bounds__(256) void cvt_f32_bf16(
    const float* __restrict__ x, bf16* __restrict__ o, int n4)
{
    const int i = blockIdx.x * 256 + threadIdx.x;
    if (i >= n4) return;
    const float4 v = ((const float4*)x)[i];
    bf16x4 b;
    b[0] = (bf16)v.x; b[1] = (bf16)v.y; b[2] = (bf16)v.z; b[3] = (bf16)v.w;
    ((bf16x4*)o)[i] = b;
}

// Weights transpose -> bf16; z==4 slice zeroes rowsum + packs bcat=bq|bk|bv.
__global__ __launch_bounds__(256) void transpose4(
    const float* __restrict__ Wq, const float* __restrict__ Wk,
    const float* __restrict__ Wv, const float* __restrict__ Wo,
    bf16* __restrict__ Wcat, bf16* __restrict__ Wto,
    const float* __restrict__ bq, const float* __restrict__ bk,
    const float* __restrict__ bv, float* __restrict__ bcat,
    float* __restrict__ rowsum)
{
    const int widx = blockIdx.z;
    const int t0 = threadIdx.x;
    if (widx == 4) {
        const int idx = (blockIdx.y * 8 + blockIdx.x) * 256 + t0;
        rowsum[idx] = 0.0f;
        if (idx < 1536)
            bcat[idx] = (idx < 512) ? bq[idx]
                      : (idx < 1024) ? bk[idx - 512] : bv[idx - 1024];
        return;
    }
    __shared__ bf16 tile[64][65];
    const float* W = (widx == 0) ? Wq : (widx == 1) ? Wk : (widx == 2) ? Wv : Wo;
    bf16* dst = (widx < 3) ? (Wcat + (size_t)widx * 512 * 512) : Wto;
    const int tx = blockIdx.x, ty = blockIdx.y;
#pragma unroll
    for (int it = 0; it < 16; ++it) {
        const int e = it * 256 + t0;
        const int r = e >> 6, c = e & 63;
        tile[r][c] = (bf16)W[(size_t)(ty * 64 + r) * 512 + tx * 64 + c];
    }
    __syncthreads();
#pragma unroll
    for (int it = 0; it < 16; ++it) {
        const int e = it * 256 + t0;
        const int o = e >> 6, i = e & 63;
        dst[(size_t)(tx * 64 + o) * 512 + ty * 64 + i] = tile[i][o];
    }
}

// ---------------------------------------------------------------------------
extern "C" void kernel_launch(void* const* d_in, const int* in_sizes, int n_in,
                              void* d_out, int out_size, void* d_ws, size_t ws_size,
                              hipStream_t stream)
{
    const float* x  = (const float*)d_in[0];
    const float* Wq = (const float*)d_in[1];
    const float* bq = (const float*)d_in[2];
    const float* Wk = (const float*)d_in[3];
    const float* bk = (const float*)d_in[4];
    const float* Wv = (const float*)d_in[5];
    const float* bv = (const float*)d_in[6];
    const float* Wo = (const float*)d_in[7];
    const float* bo = (const float*)d_in[8];
    float* out = (float*)d_out;

    char* ws = (char*)d_ws;
    bf16*    Xb     = (bf16*)(ws);              // 16 MB; dead after QKV GEMM
    bf16*    Ctx    = (bf16*)(ws);              // reuses Xb (PV output)
    bf16*    Wcat   = (bf16*)(ws + 16777216);   // 1536x512 bf16 (Wq^T|Wk^T|Wv^T)
    bf16*    Wto    = (bf16*)(ws + 18350080);   // 0.5 MB Wo^T
    float*   bcat   = (float*)(ws + 18874368);  // 1536 fp32 (bq|bk|bv)
    float*   rowsum = (float*)(ws + 18880512);  // 64 KB
    uint8_t* Q8     = (uint8_t*)(ws + 20971520);  // Q8|K8|V8 fp8, 8 MB each
    uint8_t* K8     = (uint8_t*)(ws + 29360128);
    uint8_t* V8     = (uint8_t*)(ws + 37748736);
    uint8_t* Vt8    = (uint8_t*)(ws + 54525952);  // [8][512][2048] fp8, 8 MB
    uint8_t* S8     = (uint8_t*)(ws + 62914560);  // [8][2048][2048] fp8, 33.5 MB

    // prologue
    transpose4<<<dim3(8, 8, 5), 256, 0, stream>>>(
        Wq, Wk, Wv, Wo, Wcat, Wto, bq, bk, bv, bcat, rowsum);
    cvt_f32_bf16<<<8192, 256, 0, stream>>>(x, Xb, 2097152);

    const float scale = 0.044194173824159216f;  // 512^-0.5

    // Fused QKV projection (bf16 MFMA): writes Q8/K8/V8 fp8(x32) directly
    gemm_bt<3, 2><<<1536, 256, 0, stream>>>(
        Xb, Wcat, Q8, bcat, 1536, 512, 12);

    // V8 -> Vt8 byte-permute transpose
    transpose_v8<<<dim3(8, 32, 8), 256, 0, stream>>>(V8, Vt8);

    // S8 = e4m3(exp(scale/1024 * Q8 @ K8^T)) + row sums; per batch 2048x2048
    gemm_mx<4><<<2048, 256, 0, stream>>>(
        Q8, K8, S8, rowsum, 2048, 512,
        2048LL * 512, 2048LL * 512, 2048LL * 2048, scale / 1024.0f, 16);

    // Ctx = (S8 @ Vt8^T) / (32*rowsum): per batch M=2048, N=512, K=2048
    gemm_mx<5><<<512, 256, 0, stream>>>(
        S8, Vt8, Ctx, rowsum, 512, 2048,
        2048LL * 2048, 512LL * 2048, 2048LL * 512, 1.0f, 4);

    // Out = Ctx @ Wo^T + bo (bf16 MFMA, fp32 out): M=16384, N=512, K=512
    gemm_bt<2, 2><<<512, 256, 0, stream>>>(
        Ctx, Wto, out, bo, 512, 512, 4);
}

// Round 12
// 219.333 us; speedup vs baseline: 1.1193x; 1.0123x over previous
//
#include <hip/hip_runtime.h>
#include <hip/hip_bf16.h>
#include <hip/hip_fp8.h>
#include <stdint.h>

typedef __bf16 bf16;
typedef __attribute__((ext_vector_type(8))) short short8;
typedef __attribute__((ext_vector_type(4))) float f32x4;
typedef __attribute__((ext_vector_type(4))) bf16 bf16x4;
typedef __attribute__((ext_vector_type(8))) int int8v;
typedef __attribute__((ext_vector_type(4))) int int4v;

#define DIM 512
#define NBATCH 8
#define SEQ 2048

// async global->LDS, 16B per lane; LDS dest must be wave-uniform base + lane*16
__device__ __forceinline__ void gld_lds16(const void* g, void* l) {
    __builtin_amdgcn_global_load_lds(
        (const __attribute__((address_space(1))) void*)g,
        (__attribute__((address_space(3))) void*)l,
        16, 0, 0);
}

__device__ __forceinline__ unsigned char f32_to_e4m3(float v) {
#if __has_builtin(__builtin_amdgcn_cvt_pk_fp8_f32)
    return (unsigned char)(__builtin_amdgcn_cvt_pk_fp8_f32(v, v, 0, false) & 0xff);
#else
    return __hip_cvt_float_to_fp8(v, __HIP_SATFINITE, __HIP_E4M3);
#endif
}

// ---------------------------------------------------------------------------
// bf16 bt-GEMM: 128x128 tile, BK=64, double-buffered LDS, plain launch bounds
// (R9/R10 A-B: (256,3) hint = 15% regression, allocator freedom wins).
// MODE 2: C fp32 row-major [M][N], +bias  (out-projection).
// MODE 3: QKV split, all fp8(x32):
//         sub 0/1 (Q/K): row-major [16384][512] at Cv + sub*8388608.
//         sub 2 (V): written TRANSPOSED directly to Vt[(b*512+f)*2048+n]
//         via a [128][144] LDS tile — kills the separate transpose dispatch.
// SWIZ 2: 1D grid, xcd=g&7; column-sibling blocks share an XCD (L2 reuse).
// ---------------------------------------------------------------------------
template <int MODE, int SWIZ>
__global__ __launch_bounds__(256) void gemm_bt(
    const bf16* __restrict__ A, const bf16* __restrict__ Bt,
    void* __restrict__ Cv, uint8_t* __restrict__ Vt,
    const float* __restrict__ bias, int N, int K, int gx)
{
    __shared__ bf16 smem[32768];         // 64 KB
    bf16* Asb = smem;
    bf16* Bsb = smem + 16384;

    int bx, by;
    {
        const unsigned g = blockIdx.x;
        const unsigned xcd = g & 7;
        const unsigned t = g >> 3;
        const unsigned per = (gridDim.x >> 3) / (unsigned)gx;
        by = xcd * per + t / (unsigned)gx;
        bx = t % (unsigned)gx;
    }

    const int tid  = threadIdx.x;
    const int lane = tid & 63;
    const int w    = tid >> 6;
    const int wr   = w >> 1;
    const int wc   = w & 1;
    const int lm   = lane & 15;
    const int lk   = lane >> 4;
    const int fs   = lm & 7;
    const int rq   = tid >> 3;
    const int pc   = tid & 7;
    const int scol = ((pc ^ (rq & 7)) * 8);

    const bf16* Ag = A + (size_t)(by * 128) * K;
    const bf16* Bg = Bt + (size_t)(bx * 128) * K;

    f32x4 acc[4][4];
#pragma unroll
    for (int i = 0; i < 4; ++i)
#pragma unroll
        for (int j = 0; j < 4; ++j)
            acc[i][j] = (f32x4){0.f, 0.f, 0.f, 0.f};

    auto stage = [&](int kb, int buf) {
#pragma unroll
        for (int t = 0; t < 4; ++t) {
            const int r = t * 32 + rq;
            gld_lds16(Ag + (size_t)r * K + kb + scol,
                      Asb + buf * 8192 + t * 2048 + tid * 8);
            gld_lds16(Bg + (size_t)r * K + kb + scol,
                      Bsb + buf * 8192 + t * 2048 + tid * 8);
        }
    };
    auto compute = [&](int buf) {
        const bf16* Ab = Asb + buf * 8192;
        const bf16* Bb = Bsb + buf * 8192;
#pragma unroll
        for (int s = 0; s < 2; ++s) {
            const int u = ((s * 4 + lk) ^ fs) * 8;
            short8 fa[4], fb[4];
#pragma unroll
            for (int i = 0; i < 4; ++i)
                fa[i] = *(const short8*)&Ab[(wr * 64 + i * 16 + lm) * 64 + u];
#pragma unroll
            for (int j = 0; j < 4; ++j)
                fb[j] = *(const short8*)&Bb[(wc * 64 + j * 16 + lm) * 64 + u];
#pragma unroll
            for (int i = 0; i < 4; ++i)
#pragma unroll
                for (int j = 0; j < 4; ++j)
                    acc[i][j] = __builtin_amdgcn_mfma_f32_16x16x32_bf16(
                        fa[i], fb[j], acc[i][j], 0, 0, 0);
        }
    };

    stage(0, 0);
    __syncthreads();
    const int E = K >> 6;
#pragma unroll 2
    for (int e = 0; e < E; ++e) {
        if (e + 1 < E) stage((e + 1) << 6, (e + 1) & 1);
        compute(e & 1);
        __syncthreads();
    }

    // bias add
#pragma unroll
    for (int i = 0; i < 4; ++i)
#pragma unroll
        for (int j = 0; j < 4; ++j) {
            const int col = bx * 128 + wc * 64 + j * 16 + lm;
            const float bv = bias[col];
#pragma unroll
            for (int r = 0; r < 4; ++r)
                acc[i][j][r] += bv;
        }

    if (MODE == 2) {
        // fp32 out via LDS-coalesced float4 stores; ft = [64][132] floats
        float* ft = (float*)smem;
        float* outp = (float*)Cv;
#pragma unroll
        for (int h = 0; h < 2; ++h) {
            if (wr == h) {
#pragma unroll
                for (int i = 0; i < 4; ++i)
#pragma unroll
                    for (int j = 0; j < 4; ++j)
#pragma unroll
                        for (int r = 0; r < 4; ++r)
                            ft[(i * 16 + lk * 4 + r) * 132 + wc * 64 + j * 16 + lm] =
                                acc[i][j][r];
            }
            __syncthreads();
            const int rr = tid >> 5, cc = (tid & 31) * 4;
#pragma unroll
            for (int p = 0; p < 8; ++p) {
                const int row = p * 8 + rr;
                *(float4*)&outp[(size_t)(by * 128 + h * 64 + row) * N +
                                bx * 128 + cc] = *(const float4*)&ft[row * 132 + cc];
            }
            __syncthreads();
        }
        return;
    }

    // MODE 3
    const int sub  = (bx * 128) >> 9;          // 0=Q 1=K 2=V
    const int col0 = (bx * 128) & 511;

    if (sub == 2) {
        // V: transposed fp8 write -> Vt[(b*512 + col0+f)*2048 + n]
        // [128 f][144 pad] LDS tile; byte-write stride 144 B = bank step 4
        // (2-way across a 16-lane quad = free); reads/stores uint4-coalesced.
        const int b  = (by * 128) >> 11;
        const int n0 = (by * 128) & 2047;
        uint8_t* t8 = (uint8_t*)smem;
#pragma unroll
        for (int i = 0; i < 4; ++i)
#pragma unroll
            for (int j = 0; j < 4; ++j)
#pragma unroll
                for (int r = 0; r < 4; ++r) {
                    const int fl = wc * 64 + j * 16 + lm;      // feature
                    const int nl = wr * 64 + i * 16 + lk * 4 + r;  // token
                    t8[fl * 144 + nl] = f32_to_e4m3(32.0f * acc[i][j][r]);
                }
        __syncthreads();
        const int f = tid >> 1, nh = (tid & 1) * 64;
#pragma unroll
        for (int p = 0; p < 4; ++p) {
            const uint4 raw = *(const uint4*)&t8[f * 144 + nh + p * 16];
            *(uint4*)&Vt[((size_t)(b * 512 + col0 + f)) * 2048 +
                         n0 + nh + p * 16] = raw;
        }
        return;
    }

    // Q/K: row-major fp8 writer via LDS [64][144] tile halves
    uint8_t* d8 = (uint8_t*)Cv + (size_t)sub * 8388608;
    uint8_t* t8 = (uint8_t*)smem;
#pragma unroll
    for (int h = 0; h < 2; ++h) {
        if (wr == h) {
#pragma unroll
            for (int i = 0; i < 4; ++i)
#pragma unroll
                for (int j = 0; j < 4; ++j)
#pragma unroll
                    for (int r = 0; r < 4; ++r)
                        t8[(i * 16 + lk * 4 + r) * 144 + wc * 64 + j * 16 + lm] =
                            f32_to_e4m3(32.0f * acc[i][j][r]);
        }
        __syncthreads();
        const int rr = tid >> 3, cc = (tid & 7) * 16;
#pragma unroll
        for (int p = 0; p < 2; ++p) {
            const int row = p * 32 + rr;
            const uint4 raw = *(const uint4*)&t8[row * 144 + cc];
            *(uint4*)&d8[(size_t)(by * 128 + h * 64 + row) * 512 + col0 + cc] =
                raw;
        }
        __syncthreads();
    }
}

// ---------------------------------------------------------------------------
// MX fp8 bt-GEMM (attention): 128x128 tile, BK=128, DOUBLE-BUFFERED (64 KB).
// R11 showed the single-buffered 4-epoch K-loop leaves each epoch's load
// latency naked (no pipe >31% busy, ~1.75 blocks/CU resident). Loads for
// epoch e+1 issue before compute(e); the end-of-epoch barrier drains them
// after the MFMAs. LDS 64 KB caps 2 blocks/CU — below the measured average
// anyway, so the m132 cliff shouldn't bind.
// mfma_scale_f32_16x16x128_f8f6f4, unit e8m0 scales (127) = plain e4m3 GEMM.
// MODE 4: S8 = e4m3(exp(alpha*acc)); fp32 row sums atomicAdd into rsum.
// MODE 5: C bf16 = acc / (32*rsum[row])  (PV + normalize; V scale folds).
// ---------------------------------------------------------------------------
template <int MODE>
__global__ __launch_bounds__(256) void gemm_mx(
    const uint8_t* __restrict__ A, const uint8_t* __restrict__ Bt,
    void* __restrict__ Cv, float* __restrict__ rsum,
    int N, int K, long long sA, long long sB, long long sC, float alpha,
    int gx)
{
    __shared__ uint8_t smem[65536];
    uint8_t* Asb = smem;                 // two 16384-B buffers
    uint8_t* Bsb = smem + 32768;

    int bx, by, bz;
    {
        const unsigned g = blockIdx.x;
        bz = g & 7;
        const unsigned r = g >> 3;
        bx = r % (unsigned)gx;
        by = r / (unsigned)gx;
    }

    const int tid  = threadIdx.x;
    const int lane = tid & 63;
    const int w    = tid >> 6;
    const int wr   = w >> 1;
    const int wc   = w & 1;
    const int lm   = lane & 15;
    const int lk   = lane >> 4;
    const int rq   = tid >> 3;
    const int pc   = tid & 7;
    const int ssrc = (pc ^ (rq & 7)) * 16;
    const int ca   = ((2 * lk) ^ (lm & 7)) * 16;
    const int cb   = ((2 * lk + 1) ^ (lm & 7)) * 16;

    const size_t z = bz;
    const uint8_t* Ag = A + z * (size_t)sA + (size_t)(by * 128) * K;
    const uint8_t* Bg = Bt + z * (size_t)sB + (size_t)(bx * 128) * K;

    f32x4 acc[4][4];
#pragma unroll
    for (int i = 0; i < 4; ++i)
#pragma unroll
        for (int j = 0; j < 4; ++j)
            acc[i][j] = (f32x4){0.f, 0.f, 0.f, 0.f};

    auto stage = [&](int kb, int buf) {
#pragma unroll
        for (int t = 0; t < 4; ++t) {
            const int r = t * 32 + rq;
            gld_lds16(Ag + (size_t)r * K + kb + ssrc,
                      Asb + buf * 16384 + t * 4096 + tid * 16);
            gld_lds16(Bg + (size_t)r * K + kb + ssrc,
                      Bsb + buf * 16384 + t * 4096 + tid * 16);
        }
    };
    auto compute = [&](int buf) {
        const uint8_t* As = Asb + buf * 16384;
        const uint8_t* Bs = Bsb + buf * 16384;
        int8v fa[4];
#pragma unroll
        for (int i = 0; i < 4; ++i) {
            const uint8_t* rp = As + (wr * 64 + i * 16 + lm) * 128;
            const int4v lo = *(const int4v*)(rp + ca);
            const int4v hi = *(const int4v*)(rp + cb);
            fa[i] = (int8v){lo[0], lo[1], lo[2], lo[3], hi[0], hi[1], hi[2], hi[3]};
        }
#pragma unroll
        for (int j = 0; j < 4; ++j) {
            const uint8_t* rp = Bs + (wc * 64 + j * 16 + lm) * 128;
            const int4v lo = *(const int4v*)(rp + ca);
            const int4v hi = *(const int4v*)(rp + cb);
            const int8v fb = (int8v){lo[0], lo[1], lo[2], lo[3],
                                     hi[0], hi[1], hi[2], hi[3]};
#pragma unroll
            for (int i = 0; i < 4; ++i)
                acc[i][j] = __builtin_amdgcn_mfma_scale_f32_16x16x128_f8f6f4(
                    fa[i], fb, acc[i][j], 0, 0, 0, 127, 0, 127);
        }
    };

    stage(0, 0);
    __syncthreads();
    const int E = K >> 7;
#pragma unroll 2
    for (int e = 0; e < E; ++e) {
        if (e + 1 < E) stage((e + 1) << 7, (e + 1) & 1);
        compute(e & 1);
        __syncthreads();
    }

    const int orow0 = by * 128 + wr * 64;

    if (MODE == 4) {
#pragma unroll
        for (int i = 0; i < 4; ++i) {
            float psum[4] = {0.f, 0.f, 0.f, 0.f};
#pragma unroll
            for (int j = 0; j < 4; ++j)
#pragma unroll
                for (int r = 0; r < 4; ++r) {
                    const float e = __expf(acc[i][j][r] * alpha);
                    acc[i][j][r] = e;
                    psum[r] += e;
                }
#pragma unroll
            for (int m = 1; m < 16; m <<= 1)
#pragma unroll
                for (int r = 0; r < 4; ++r) psum[r] += __shfl_xor(psum[r], m);
            if (lm == 0) {
#pragma unroll
                for (int r = 0; r < 4; ++r)
                    atomicAdd(&rsum[z * SEQ + orow0 + i * 16 + lk * 4 + r],
                              psum[r]);
            }
        }
        uint8_t* dst = (uint8_t*)Cv + z * (size_t)sC;
#pragma unroll
        for (int h = 0; h < 2; ++h) {
            if (wr == h) {
#pragma unroll
                for (int i = 0; i < 4; ++i)
#pragma unroll
                    for (int j = 0; j < 4; ++j)
#pragma unroll
                        for (int r = 0; r < 4; ++r)
                            smem[(i * 16 + lk * 4 + r) * 144 +
                                 wc * 64 + j * 16 + lm] =
                                f32_to_e4m3(acc[i][j][r]);
            }
            __syncthreads();
            const int rr = tid >> 3, cc = (tid & 7) * 16;
#pragma unroll
            for (int p = 0; p < 2; ++p) {
                const int row = p * 32 + rr;
                const uint4 raw = *(const uint4*)&smem[row * 144 + cc];
                *(uint4*)&dst[(size_t)(by * 128 + h * 64 + row) * N +
                              bx * 128 + cc] = raw;
            }
            __syncthreads();
        }
        return;
    }

    // MODE 5: normalize by 32*rowsum, bf16 out via LDS [64][136] tile
#pragma unroll
    for (int i = 0; i < 4; ++i) {
        float inv[4];
#pragma unroll
        for (int r = 0; r < 4; ++r)
            inv[r] = 1.0f / (32.0f * rsum[z * SEQ + orow0 + i * 16 + lk * 4 + r]);
#pragma unroll
        for (int j = 0; j < 4; ++j)
#pragma unroll
            for (int r = 0; r < 4; ++r)
                acc[i][j][r] *= inv[r];
    }
    bf16* dst = (bf16*)Cv + z * (size_t)sC;
    bf16* tile = (bf16*)smem;
#pragma unroll
    for (int h = 0; h < 2; ++h) {
        if (wr == h) {
#pragma unroll
            for (int i = 0; i < 4; ++i)
#pragma unroll
                for (int j = 0; j < 4; ++j)
#pragma unroll
                    for (int r = 0; r < 4; ++r)
                        tile[(i * 16 + lk * 4 + r) * 136 + wc * 64 + j * 16 + lm] =
                            (bf16)acc[i][j][r];
        }
        __syncthreads();
        const int rr0 = tid >> 4, cc = (tid & 15) * 8;
#pragma unroll
        for (int p = 0; p < 4; ++p) {
            const int row = p * 16 + rr0;
            const uint4 raw = *(const uint4*)&tile[row * 136 + cc];
            *(uint4*)&dst[(size_t)(by * 128 + h * 64 + row) * N + bx * 128 + cc] =
                raw;
        }
        __syncthreads();
    }
}

// ---------------------------------------------------------------------------
__global__ __launch_bounds__(256) void cvt_f32_bf16(
    const float* __restrict__ x, bf16* __restrict__ o, int n4)
{
    const int i = blockIdx.x * 256 + threadIdx.x;
    if (i >= n4) return;
    const float4 v = ((const float4*)x)[i];
    bf16x4 b;
    b[0] = (bf16)v.x; b[1] = (bf16)v.y; b[2] = (bf16)v.z; b[3] = (bf16)v.w;
    ((bf16x4*)o)[i] = b;
}

// Weights transpose -> bf16; z==4 slice zeroes rowsum + packs bcat=bq|bk|bv.
__global__ __launch_bounds__(256) void transpose4(
    const float* __restrict__ Wq, const float* __restrict__ Wk,
    const float* __restrict__ Wv, const float* __restrict__ Wo,
    bf16* __restrict__ Wcat, bf16* __restrict__ Wto,
    const float* __restrict__ bq, const float* __restrict__ bk,
    const float* __restrict__ bv, float* __restrict__ bcat,
    float* __restrict__ rowsum)
{
    const int widx = blockIdx.z;
    const int t0 = threadIdx.x;
    if (widx == 4) {
        const int idx = (blockIdx.y * 8 + blockIdx.x) * 256 + t0;
        rowsum[idx] = 0.0f;
        if (idx < 1536)
            bcat[idx] = (idx < 512) ? bq[idx]
                      : (idx < 1024) ? bk[idx - 512] : bv[idx - 1024];
        return;
    }
    __shared__ bf16 tile[64][65];
    const float* W = (widx == 0) ? Wq : (widx == 1) ? Wk : (widx == 2) ? Wv : Wo;
    bf16* dst = (widx < 3) ? (Wcat + (size_t)widx * 512 * 512) : Wto;
    const int tx = blockIdx.x, ty = blockIdx.y;
#pragma unroll
    for (int it = 0; it < 16; ++it) {
        const int e = it * 256 + t0;
        const int r = e >> 6, c = e & 63;
        tile[r][c] = (bf16)W[(size_t)(ty * 64 + r) * 512 + tx * 64 + c];
    }
    __syncthreads();
#pragma unroll
    for (int it = 0; it < 16; ++it) {
        const int e = it * 256 + t0;
        const int o = e >> 6, i = e & 63;
        dst[(size_t)(tx * 64 + o) * 512 + ty * 64 + i] = tile[i][o];
    }
}

// ---------------------------------------------------------------------------
extern "C" void kernel_launch(void* const* d_in, const int* in_sizes, int n_in,
                              void* d_out, int out_size, void* d_ws, size_t ws_size,
                              hipStream_t stream)
{
    const float* x  = (const float*)d_in[0];
    const float* Wq = (const float*)d_in[1];
    const float* bq = (const float*)d_in[2];
    const float* Wk = (const float*)d_in[3];
    const float* bk = (const float*)d_in[4];
    const float* Wv = (const float*)d_in[5];
    const float* bv = (const float*)d_in[6];
    const float* Wo = (const float*)d_in[7];
    const float* bo = (const float*)d_in[8];
    float* out = (float*)d_out;

    char* ws = (char*)d_ws;
    bf16*    Xb     = (bf16*)(ws);              // 16 MB; dead after QKV GEMM
    bf16*    Ctx    = (bf16*)(ws);              // reuses Xb (PV output)
    bf16*    Wcat   = (bf16*)(ws + 16777216);   // 1536x512 bf16 (Wq^T|Wk^T|Wv^T)
    bf16*    Wto    = (bf16*)(ws + 18350080);   // 0.5 MB Wo^T
    float*   bcat   = (float*)(ws + 18874368);  // 1536 fp32 (bq|bk|bv)
    float*   rowsum = (float*)(ws + 18880512);  // 64 KB
    uint8_t* Q8     = (uint8_t*)(ws + 20971520);  // Q8|K8 fp8, 8 MB each
    uint8_t* K8     = (uint8_t*)(ws + 29360128);
    uint8_t* Vt8    = (uint8_t*)(ws + 54525952);  // [8][512][2048] fp8, 8 MB
    uint8_t* S8     = (uint8_t*)(ws + 62914560);  // [8][2048][2048] fp8, 33.5 MB

    // prologue
    transpose4<<<dim3(8, 8, 5), 256, 0, stream>>>(
        Wq, Wk, Wv, Wo, Wcat, Wto, bq, bk, bv, bcat, rowsum);
    cvt_f32_bf16<<<8192, 256, 0, stream>>>(x, Xb, 2097152);

    const float scale = 0.044194173824159216f;  // 512^-0.5

    // Fused QKV projection (bf16 MFMA): Q8/K8 row-major fp8(x32), V written
    // transposed straight into Vt8 (no separate transpose dispatch).
    gemm_bt<3, 2><<<1536, 256, 0, stream>>>(
        Xb, Wcat, Q8, Vt8, bcat, 1536, 512, 12);

    // S8 = e4m3(exp(scale/1024 * Q8 @ K8^T)) + row sums; per batch 2048x2048
    gemm_mx<4><<<2048, 256, 0, stream>>>(
        Q8, K8, S8, rowsum, 2048, 512,
        2048LL * 512, 2048LL * 512, 2048LL * 2048, scale / 1024.0f, 16);

    // Ctx = (S8 @ Vt8^T) / (32*rowsum): per batch M=2048, N=512, K=2048
    gemm_mx<5><<<512, 256, 0, stream>>>(
        S8, Vt8, Ctx, rowsum, 512, 2048,
        2048LL * 2048, 512LL * 2048, 2048LL * 512, 1.0f, 4);

    // Out = Ctx @ Wo^T + bo (bf16 MFMA, fp32 out): M=16384, N=512, K=512
    gemm_bt<2, 2><<<512, 256, 0, stream>>>(
        Ctx, Wto, out, nullptr, bo, 512, 512, 4);
}